// Round 7
// baseline (311.322 us; speedup 1.0000x reference)
//
#include <hip/hip_runtime.h>
#include <hip/hip_bf16.h>
#include <math.h>

#define Bdim 32
#define Adim 256
#define Ndim 64
#define Gdim 50
#define Fdim 128

typedef __attribute__((ext_vector_type(8)))  short short8;
typedef __attribute__((ext_vector_type(16))) float floatx16;

__device__ __forceinline__ unsigned short f2bf_u(float x) {
    __hip_bfloat16 h = __float2bfloat16(x);
    return __builtin_bit_cast(unsigned short, h);
}
__device__ __forceinline__ unsigned pk2bf(float a, float b) {
    return (unsigned)f2bf_u(a) | ((unsigned)f2bf_u(b) << 16);
}
__device__ __forceinline__ float bf2f_lo(unsigned u) {   // low bf16 of packed u32
    return __builtin_bit_cast(float, u << 16);
}
__device__ __forceinline__ float bf2f_hi(unsigned u) {   // high bf16 of packed u32
    return __builtin_bit_cast(float, u & 0xFFFF0000u);
}
// shifted softplus = ln2*log2(1+e^v) - ln2.  5 ops / 2 trans. (verified)
__device__ __forceinline__ float sspf(float v) {
    float t = __expf(v);
    return fmaf(__log2f(1.0f + t), 0.69314718056f, -0.69314718056f);
}
__device__ __forceinline__ short8 mk8(unsigned a, unsigned b, unsigned c, unsigned d) {
    union { unsigned u[4]; short8 s; } t;
    t.u[0] = a; t.u[1] = b; t.u[2] = c; t.u[3] = d;
    return t.s;
}

// ---------------------------------------------------------------------------
// Kernel 1 v3: y = x @ in2f_w, spread over 256 blocks (was 64 -> 4x CUs).
//   Block b (<256): rows rb = b*32..b*32+31; wave wv computes jt = wv
//   (f = wv*32+lm), acc = 16 regs. y stored INTERLEAVED (unchanged layout):
//   y2[row*128 + lm*4 + jt] holds f = jt*32+lm.
// Block 256: fw1T bf16 table [f][g0..63] (bias col g=50, zeros after).
// Block 257: fw2T bf16 table [f][h0..127].
// ---------------------------------------------------------------------------
__global__ __launch_bounds__(256) void in2f_mfma3(const float* __restrict__ x,
                                                  const float* __restrict__ w,
                                                  unsigned short* __restrict__ y,
                                                  const float* __restrict__ fw1,
                                                  const float* __restrict__ fb1,
                                                  const float* __restrict__ fw2,
                                                  unsigned short* __restrict__ fw1t,
                                                  unsigned short* __restrict__ fw2t) {
    const int tid = threadIdx.x;
    if (blockIdx.x == 256) {
        for (int idx = tid; idx < 128 * 64; idx += 256) {
            int f = idx >> 6, g = idx & 63;
            float v = (g < Gdim) ? fw1[g * 128 + f] : ((g == Gdim) ? fb1[f] : 0.0f);
            fw1t[idx] = f2bf_u(v);
        }
        return;
    }
    if (blockIdx.x == 257) {
        for (int idx = tid; idx < 128 * 128; idx += 256) {
            int f = idx >> 7, h = idx & 127;
            fw2t[idx] = f2bf_u(fw2[h * 128 + f]);
        }
        return;
    }
    __shared__ short sWT[128 * 132];   // w^T[f][i]  33792 B
    __shared__ short sX [32 * 132];    // x[row][i]   8448 B

    // stage w^T (full, every block; L2-hot after first wave of blocks)
#pragma unroll 4
    for (int k = 0; k < 32; ++k) {
        int idx = tid + k * 256;             // float2 index, 8192 total
        float2 v = *(const float2*)(w + 2 * idx);
        int i = idx >> 6;
        int f = (2 * idx) & 127;
        sWT[f * 132 + i]       = (short)f2bf_u(v.x);
        sWT[(f + 1) * 132 + i] = (short)f2bf_u(v.y);
    }
    // stage this block's 32 x-rows: 4096 floats = 2048 float2
    const float* xb = x + (size_t)blockIdx.x * (32 * 128);
#pragma unroll
    for (int k = 0; k < 8; ++k) {
        int idx = tid + k * 256;
        float2 v = *(const float2*)(xb + 2 * idx);
        int row = idx >> 6;                  // 0..31
        int i = (2 * idx) & 127;
        *(unsigned*)&sX[row * 132 + i] = pk2bf(v.x, v.y);
    }
    __syncthreads();

    const int wv = tid >> 6, lane = tid & 63, lm = lane & 31, lh = lane >> 5;
    floatx16 acc;
#pragma unroll
    for (int e = 0; e < 16; ++e) acc[e] = 0.0f;

#pragma unroll
    for (int ks = 0; ks < 8; ++ks) {
        int g0 = ks * 16 + lh * 8;
        const short* ap = &sX[lm * 132 + g0];            // A rows = x rows = lm
        uint2 a0 = *(const uint2*)ap;
        uint2 a1 = *(const uint2*)(ap + 4);
        const short* bp = &sWT[(wv * 32 + lm) * 132 + g0];  // B rows = f
        uint2 b0 = *(const uint2*)bp;
        uint2 b1 = *(const uint2*)(bp + 4);
        acc = __builtin_amdgcn_mfma_f32_32x32x16_bf16(
            mk8(a0.x, a0.y, a1.x, a1.y), mk8(b0.x, b0.y, b1.x, b1.y), acc, 0, 0, 0);
    }
    // D: reg r -> x-row (r&3)+8*(r>>2)+4*lh, lane col lm -> f = wv*32+lm
    const int rbase = blockIdx.x * 32;
#pragma unroll
    for (int r = 0; r < 16; ++r) {
        int row = rbase + (r & 3) + 8 * (r >> 2) + 4 * lh;
        y[(size_t)row * 128 + lm * 4 + wv] = f2bf_u(acc[r]);
    }
}

// ---------------------------------------------------------------------------
// Kernel 2 v10: v9 + dense1 half-0 weights preloaded to regs + fb2-init acc2.
//  - fwf[8] (ft 0,1 x ks 0..3, 32 VGPR) loaded once per block from fw1t;
//    dense1 half-0 is pure-register MFMA (no global on critical path).
//    Half-1 keeps batched L1-hot b128 loads. Regs ~120 <= 170: no spill
//    (tripwire: VGPR_Count + WRITE_SIZE).
//  - acc2 initialized with fb2 (MFMA accumulates on top): fold becomes
//    pure *= cm; -64 VALU/body.
//  - everything else v9-verified: sFw2 LDS copy, halved wave-private W1
//    handoff, reg-direct f_ij + prefetch, interleaved-y2 epilogue.
// ---------------------------------------------------------------------------
#define SF2 132     // sFw2 stride (shorts): 66 dw -> 2-way free
#define SW1 68      // handoff stride (shorts): 34 dw -> 2-way free, 8B-align
#define NSP 4096    // total super-pairs (B*A/2)
#define GRID2 2048

struct FijRegs { float2 p[13]; };

__device__ __forceinline__ FijRegs load_fij(const float* __restrict__ f_ij,
                                            int sp, int row, int lh) {
    FijRegs F;
    const float* base = f_ij + (size_t)sp * (2 * Ndim * Gdim) + row * Gdim;
#pragma unroll
    for (int ks = 0; ks < 3; ++ks) {
        int g0 = 16 * ks + 8 * lh;
#pragma unroll
        for (int j = 0; j < 4; ++j)
            F.p[ks * 4 + j] = *(const float2*)(base + g0 + 2 * j);
    }
    F.p[12] = *(const float2*)(base + 48);   // both lh halves: g=48,49
    return F;
}

// convert raw f_ij regs -> 4 packed bf16 MFMA B-frags
__device__ __forceinline__ void cvt_fij(const FijRegs& F, int lh, short8 bfr[4]) {
#pragma unroll
    for (int ks = 0; ks < 3; ++ks)
        bfr[ks] = mk8(pk2bf(F.p[ks*4+0].x, F.p[ks*4+0].y),
                      pk2bf(F.p[ks*4+1].x, F.p[ks*4+1].y),
                      pk2bf(F.p[ks*4+2].x, F.p[ks*4+2].y),
                      pk2bf(F.p[ks*4+3].x, F.p[ks*4+3].y));
    // ks=3: lh=0 holds g=48,49, bias 1.0 at g=50, zeros; lh=1 all zero
    unsigned u0 = lh ? 0u : pk2bf(F.p[12].x, F.p[12].y);
    unsigned u1 = lh ? 0u : 0x00003F80u;
    bfr[3] = mk8(u0, u1, 0u, 0u);
}

__device__ __forceinline__ void cf_body(
    int sp, int par, const short8 bfr[4], int nsp, short8 bfrN[4],
    const short8 fwf[8],
    const float* __restrict__ f_ij, const float* __restrict__ r_ij,
    const float* __restrict__ mask, const int* __restrict__ nbr,
    const unsigned short* __restrict__ fw1t,
    const unsigned short* __restrict__ ybf, float* __restrict__ out,
    float4 fb2v, short* sW1w, const short* sFw2, float (*sRed)[2][128],
    int wv, int lm, int lh, int row)
{
    // acc2 initialized with fb2 (f = jt*32+lm -> fb2v[jt]); MFMA adds on top
    floatx16 acc2[4];
#pragma unroll
    for (int jt = 0; jt < 4; ++jt) {
        float fb2j = (jt == 0) ? fb2v.x : (jt == 1) ? fb2v.y
                   : (jt == 2) ? fb2v.z : fb2v.w;
#pragma unroll
        for (int e = 0; e < 16; ++e) acc2[jt][e] = fb2j;
    }

    FijRegs Fl;
#pragma unroll
    for (int half = 0; half < 2; ++half) {
        // ---- dense1 half: ft = half*2 + {0,1}; A = fw1T (half 0: regs,
        // half 1: global b128 L1-hot), B = f_ij (regs). Results packed
        // into wave-private handoff chunk (h-local 0..63). ----
#pragma unroll
        for (int ftl = 0; ftl < 2; ++ftl) {
            const int ft = half * 2 + ftl;
            floatx16 a1;
#pragma unroll
            for (int e = 0; e < 16; ++e) a1[e] = 0.0f;
            if (half == 0) {
#pragma unroll
                for (int ks = 0; ks < 4; ++ks)
                    a1 = __builtin_amdgcn_mfma_f32_32x32x16_bf16(
                        fwf[ftl * 4 + ks], bfr[ks], a1, 0, 0, 0);
            } else {
                const unsigned short* fwp = fw1t + ((ft * 32 + lm) * 64 + lh * 8);
#pragma unroll
                for (int ks = 0; ks < 4; ++ks) {
                    short8 a = *(const short8*)(fwp + ks * 16);
                    a1 = __builtin_amdgcn_mfma_f32_32x32x16_bf16(a, bfr[ks], a1, 0, 0, 0);
                }
            }
            // D1 layout: col=lane&31=n; h = (reg&3)+8*(reg>>2)+4*lh (+32*ft)
#pragma unroll
            for (int q = 0; q < 8; ++q) {
                unsigned P = pk2bf(sspf(a1[2 * q]), sspf(a1[2 * q + 1]));
                int hl = ftl * 32 + 4 * lh + 8 * (q >> 1) + 2 * (q & 1);
                *(unsigned*)&sW1w[lm * SW1 + hl] = P;
            }
        }
        // ---- prefetch next body's f_ij once per body (covered by
        // dense2B + epilogue) ----
        if (half == 1 && nsp >= 0) Fl = load_fij(f_ij, nsp, row, lh);

        // ---- dense2 half: A = W1 chunk (LDS b64 pairs), B = fw2T (LDS) ----
#pragma unroll
        for (int ksl = 0; ksl < 4; ++ksl) {
            const short* ap = &sW1w[lm * SW1 + ksl * 16 + lh * 8];
            uint2 a0 = *(const uint2*)ap;
            uint2 a1v = *(const uint2*)(ap + 4);
            short8 a = mk8(a0.x, a0.y, a1v.x, a1v.y);
            const int ks = half * 4 + ksl;
#pragma unroll
            for (int jt = 0; jt < 4; ++jt) {
                const short* bp = &sFw2[(jt * 32 + lm) * SF2 + ks * 16 + lh * 8];
                uint2 b0 = *(const uint2*)bp;
                uint2 b1 = *(const uint2*)(bp + 4);
                acc2[jt] = __builtin_amdgcn_mfma_f32_32x32x16_bf16(
                    a, mk8(b0.x, b0.y, b1.x, b1.y), acc2[jt], 0, 0, 0);
            }
        }
    }

    // ---- convert prefetched f_ij now (loads long landed) ----
    if (nsp >= 0) cvt_fij(Fl, lh, bfrN);

    // ---- cutoff*mask + neighbor indices: broadcast loads, in-reg cos ----
    const int site = sp * 2 + (wv >> 1);
    float cmv[16]; int nbv[16];
#pragma unroll
    for (int rq = 0; rq < 4; ++rq) {
        int off = site * Ndim + (wv & 1) * 32 + rq * 8 + lh * 4;
        float4 r4 = *(const float4*)(r_ij + off);
        float4 m4 = *(const float4*)(mask + off);
        int4   n4 = *(const int4*)(nbr + off);
        float rr[4] = { r4.x, r4.y, r4.z, r4.w };
        float mm[4] = { m4.x, m4.y, m4.z, m4.w };
        int   nn[4] = { n4.x, n4.y, n4.z, n4.w };
#pragma unroll
        for (int j = 0; j < 4; ++j) {
            float c = 0.5f * (__cosf(rr[j] * 0.62831853071796f) + 1.0f);
            c = (rr[j] < 5.0f) ? c : 0.0f;
            cmv[rq * 4 + j] = c * mm[j];
            nbv[rq * 4 + j] = nn[j];
        }
    }

    // ---- fold cm (fb2 already inside acc2); pure mul ----
#pragma unroll
    for (int jt = 0; jt < 4; ++jt)
#pragma unroll
        for (int r = 0; r < 16; ++r)
            acc2[jt][r] *= cmv[r];

    // ---- epilogue: out[f] += acc2'[jt][r] * y2[nbr[r]][lm][jt] ----
    const int bofs = (site >> 8) * Adim;
    float part[4] = {0.f, 0.f, 0.f, 0.f};
#pragma unroll
    for (int r = 0; r < 16; ++r) {
        uint2 u = *(const uint2*)(ybf + (((size_t)(bofs + nbv[r])) << 7) + lm * 4);
        part[0] = fmaf(acc2[0][r], bf2f_lo(u.x), part[0]);
        part[1] = fmaf(acc2[1][r], bf2f_hi(u.x), part[1]);
        part[2] = fmaf(acc2[2][r], bf2f_lo(u.y), part[2]);
        part[3] = fmaf(acc2[3][r], bf2f_hi(u.y), part[3]);
    }
#pragma unroll
    for (int jt = 0; jt < 4; ++jt) part[jt] += __shfl_xor(part[jt], 32);

    const int s = wv >> 1;
    if (wv & 1) {
#pragma unroll
        for (int k = 0; k < 2; ++k)
            sRed[par][s][(2 * lh + k) * 32 + lm] = part[2 * lh + k];
    }
    __syncthreads();   // only barrier per body (sRed parity-dbuf'd)
    if (!(wv & 1)) {
#pragma unroll
        for (int k = 0; k < 2; ++k) {
            int jt = 2 * lh + k;
            int f = jt * 32 + lm;
            out[(size_t)site * Fdim + f] = part[jt] + sRed[par][s][f];
        }
    }
}

__global__ __launch_bounds__(256, 3) void cfconv_mfma10(
    const float* __restrict__ r_ij, const float* __restrict__ f_ij,
    const float* __restrict__ mask, const int* __restrict__ nbr,
    const unsigned short* __restrict__ fw1t,
    const unsigned short* __restrict__ fw2t,
    const float* __restrict__ fb2,
    const unsigned short* __restrict__ ybf, float* __restrict__ out)
{
    __shared__ short sW1[4][32][SW1];       // 17408 B: per-wave W1 handoff (half)
    __shared__ short sFw2[128 * SF2];       // 33792 B: fw2T[f][h], padded
    __shared__ float sRed[2][2][128];       //  2048 B: parity x site x f
    // total 53248 B -> 3 blocks/CU (3x53248 = 159744 <= 163840)

    const int tid = threadIdx.x, wv = tid >> 6, lane = tid & 63;
    const int lm = lane & 31, lh = lane >> 5;
    const int bid = blockIdx.x;
    const int row = wv * 32 + lm;
    short* sW1w = &sW1[wv][0][0];

    // body-1 f_ij loads issued first; land while sFw2 stages
    FijRegs F0 = load_fij(f_ij, bid, row, lh);

    // preload dense1 half-0 weights (ft 0,1 x ks 0..3) -> 32 VGPR, reused
    // by both bodies; removes global loads from dense1 half-0 critical path
    short8 fwf[8];
#pragma unroll
    for (int ft = 0; ft < 2; ++ft)
#pragma unroll
        for (int ks = 0; ks < 4; ++ks)
            fwf[ft * 4 + ks] =
                *(const short8*)(fw1t + ((ft * 32 + lm) * 64 + lh * 8) + ks * 16);

    // stage sFw2 as raw bf16 copy from fw2t table.
    // 4096 uint2; 128-short row = 32 uint2 -> f = idx>>5, hq = idx&31.
#pragma unroll
    for (int k = 0; k < 16; ++k) {
        int idx = tid + k * 256;              // uint2 index over 4096
        int f = idx >> 5, hq = idx & 31;      // h = hq*4
        *(uint2*)&sFw2[f * SF2 + hq * 4] = *(const uint2*)(fw2t + f * 128 + hq * 4);
    }
    float4 fb2v;
    fb2v.x = fb2[lm]; fb2v.y = fb2[32 + lm]; fb2v.z = fb2[64 + lm]; fb2v.w = fb2[96 + lm];

    short8 bA[4], bB[4];
    cvt_fij(F0, lh, bA);
    __syncthreads();

    cf_body(bid, 0, bA, bid + GRID2, bB, fwf, f_ij, r_ij, mask, nbr,
            fw1t, ybf, out, fb2v, sW1w, sFw2, sRed, wv, lm, lh, row);
    cf_body(bid + GRID2, 1, bB, -1, bA, fwf, f_ij, r_ij, mask, nbr,
            fw1t, ybf, out, fb2v, sW1w, sFw2, sRed, wv, lm, lh, row);
}

// ---------------------------------------------------------------------------
extern "C" void kernel_launch(void* const* d_in, const int* in_sizes, int n_in,
                              void* d_out, int out_size, void* d_ws, size_t ws_size,
                              hipStream_t stream) {
    const float* x      = (const float*)d_in[0];
    const float* r_ij   = (const float*)d_in[1];
    const float* f_ij   = (const float*)d_in[2];
    const float* mask   = (const float*)d_in[3];
    const int*   nbr    = (const int*)d_in[4];
    const float* in2f_w = (const float*)d_in[5];
    const float* fw1    = (const float*)d_in[6];
    const float* fb1    = (const float*)d_in[7];
    const float* fw2    = (const float*)d_in[8];
    const float* fb2    = (const float*)d_in[9];
    float* out = (float*)d_out;
    unsigned short* y    = (unsigned short*)d_ws;                       // 2 MB bf16 y2
    unsigned short* fw1t = (unsigned short*)((char*)d_ws + (size_t)(Bdim*Adim*Fdim)*2);
    unsigned short* fw2t = fw1t + 128 * 64;                             // +16 KB -> 32 KB

    in2f_mfma3<<<258, 256, 0, stream>>>(x, in2f_w, y, fw1, fb1, fw2, fw1t, fw2t);
    cfconv_mfma10<<<GRID2, 256, 0, stream>>>(r_ij, f_ij, mask, nbr,
                                             fw1t, fw2t, fb2, y, out);
}

// Round 9
// 293.869 us; speedup vs baseline: 1.0594x; 1.0594x over previous
//
#include <hip/hip_runtime.h>
#include <hip/hip_bf16.h>
#include <math.h>

#define Bdim 32
#define Adim 256
#define Ndim 64
#define Gdim 50
#define Fdim 128

typedef __attribute__((ext_vector_type(8)))  short short8;
typedef __attribute__((ext_vector_type(16))) float floatx16;

__device__ __forceinline__ unsigned short f2bf_u(float x) {
    __hip_bfloat16 h = __float2bfloat16(x);
    return __builtin_bit_cast(unsigned short, h);
}
__device__ __forceinline__ unsigned pk2bf(float a, float b) {
    return (unsigned)f2bf_u(a) | ((unsigned)f2bf_u(b) << 16);
}
__device__ __forceinline__ float bf2f_lo(unsigned u) {   // low bf16 of packed u32
    return __builtin_bit_cast(float, u << 16);
}
__device__ __forceinline__ float bf2f_hi(unsigned u) {   // high bf16 of packed u32
    return __builtin_bit_cast(float, u & 0xFFFF0000u);
}
// shifted softplus = ln2*log2(1+e^v) - ln2.  5 ops / 2 trans. (verified)
__device__ __forceinline__ float sspf(float v) {
    float t = __expf(v);
    return fmaf(__log2f(1.0f + t), 0.69314718056f, -0.69314718056f);
}
__device__ __forceinline__ short8 mk8(unsigned a, unsigned b, unsigned c, unsigned d) {
    union { unsigned u[4]; short8 s; } t;
    t.u[0] = a; t.u[1] = b; t.u[2] = c; t.u[3] = d;
    return t.s;
}

// ---------------------------------------------------------------------------
// Kernel 1 v3 (R7-verified): y = x @ in2f_w over 256 blocks (4x CU coverage).
//   Block b (<256): rows b*32..b*32+31; wave wv computes jt = wv.
//   y stored INTERLEAVED: y2[row*128 + lm*4 + jt] holds f = jt*32+lm.
// Block 256: fw1T bf16 table [f][g0..63] (bias col g=50, zeros after).
// Block 257: fw2T bf16 table [f][h0..127].
// ---------------------------------------------------------------------------
__global__ __launch_bounds__(256) void in2f_mfma3(const float* __restrict__ x,
                                                  const float* __restrict__ w,
                                                  unsigned short* __restrict__ y,
                                                  const float* __restrict__ fw1,
                                                  const float* __restrict__ fb1,
                                                  const float* __restrict__ fw2,
                                                  unsigned short* __restrict__ fw1t,
                                                  unsigned short* __restrict__ fw2t) {
    const int tid = threadIdx.x;
    if (blockIdx.x == 256) {
        for (int idx = tid; idx < 128 * 64; idx += 256) {
            int f = idx >> 6, g = idx & 63;
            float v = (g < Gdim) ? fw1[g * 128 + f] : ((g == Gdim) ? fb1[f] : 0.0f);
            fw1t[idx] = f2bf_u(v);
        }
        return;
    }
    if (blockIdx.x == 257) {
        for (int idx = tid; idx < 128 * 128; idx += 256) {
            int f = idx >> 7, h = idx & 127;
            fw2t[idx] = f2bf_u(fw2[h * 128 + f]);
        }
        return;
    }
    __shared__ short sWT[128 * 132];   // w^T[f][i]  33792 B
    __shared__ short sX [32 * 132];    // x[row][i]   8448 B

#pragma unroll 4
    for (int k = 0; k < 32; ++k) {
        int idx = tid + k * 256;             // float2 index, 8192 total
        float2 v = *(const float2*)(w + 2 * idx);
        int i = idx >> 6;
        int f = (2 * idx) & 127;
        sWT[f * 132 + i]       = (short)f2bf_u(v.x);
        sWT[(f + 1) * 132 + i] = (short)f2bf_u(v.y);
    }
    const float* xb = x + (size_t)blockIdx.x * (32 * 128);
#pragma unroll
    for (int k = 0; k < 8; ++k) {
        int idx = tid + k * 256;
        float2 v = *(const float2*)(xb + 2 * idx);
        int row = idx >> 6;                  // 0..31
        int i = (2 * idx) & 127;
        *(unsigned*)&sX[row * 132 + i] = pk2bf(v.x, v.y);
    }
    __syncthreads();

    const int wv = tid >> 6, lane = tid & 63, lm = lane & 31, lh = lane >> 5;
    floatx16 acc;
#pragma unroll
    for (int e = 0; e < 16; ++e) acc[e] = 0.0f;

#pragma unroll
    for (int ks = 0; ks < 8; ++ks) {
        int g0 = ks * 16 + lh * 8;
        const short* ap = &sX[lm * 132 + g0];            // A rows = x rows = lm
        uint2 a0 = *(const uint2*)ap;
        uint2 a1 = *(const uint2*)(ap + 4);
        const short* bp = &sWT[(wv * 32 + lm) * 132 + g0];  // B rows = f
        uint2 b0 = *(const uint2*)bp;
        uint2 b1 = *(const uint2*)(bp + 4);
        acc = __builtin_amdgcn_mfma_f32_32x32x16_bf16(
            mk8(a0.x, a0.y, a1.x, a1.y), mk8(b0.x, b0.y, b1.x, b1.y), acc, 0, 0, 0);
    }
    const int rbase = blockIdx.x * 32;
#pragma unroll
    for (int r = 0; r < 16; ++r) {
        int row = rbase + (r & 3) + 8 * (r >> 2) + 4 * lh;
        y[(size_t)row * 128 + lm * 4 + wv] = f2bf_u(acc[r]);
    }
}

// ---------------------------------------------------------------------------
// Kernel 2 v11 = v9 (proven 85.7 us, no spill) + fb2-init acc2 only.
//  R7 lesson (3rd spill): NO block-lifetime register additions are
//  affordable — acc2(64) + v9's working set is at the (256,3)=170 cap.
//  fb2-init is reg-neutral (init constant 0 -> fb2j) and saves 64 VALU.
//  Everything else byte-identical to v9.
//  (R8 was an infra failure — container died; resubmitting unchanged.)
// ---------------------------------------------------------------------------
#define SF2 132     // sFw2 stride (shorts): 66 dw -> 2-way free
#define SW1 68      // handoff stride (shorts): 34 dw -> 2-way free, 8B-align
#define NSP 4096    // total super-pairs (B*A/2)
#define GRID2 2048

struct FijRegs { float2 p[13]; };

__device__ __forceinline__ FijRegs load_fij(const float* __restrict__ f_ij,
                                            int sp, int row, int lh) {
    FijRegs F;
    const float* base = f_ij + (size_t)sp * (2 * Ndim * Gdim) + row * Gdim;
#pragma unroll
    for (int ks = 0; ks < 3; ++ks) {
        int g0 = 16 * ks + 8 * lh;
#pragma unroll
        for (int j = 0; j < 4; ++j)
            F.p[ks * 4 + j] = *(const float2*)(base + g0 + 2 * j);
    }
    F.p[12] = *(const float2*)(base + 48);   // both lh halves: g=48,49
    return F;
}

// convert raw f_ij regs -> 4 packed bf16 MFMA B-frags
__device__ __forceinline__ void cvt_fij(const FijRegs& F, int lh, short8 bfr[4]) {
#pragma unroll
    for (int ks = 0; ks < 3; ++ks)
        bfr[ks] = mk8(pk2bf(F.p[ks*4+0].x, F.p[ks*4+0].y),
                      pk2bf(F.p[ks*4+1].x, F.p[ks*4+1].y),
                      pk2bf(F.p[ks*4+2].x, F.p[ks*4+2].y),
                      pk2bf(F.p[ks*4+3].x, F.p[ks*4+3].y));
    // ks=3: lh=0 holds g=48,49, bias 1.0 at g=50, zeros; lh=1 all zero
    unsigned u0 = lh ? 0u : pk2bf(F.p[12].x, F.p[12].y);
    unsigned u1 = lh ? 0u : 0x00003F80u;
    bfr[3] = mk8(u0, u1, 0u, 0u);
}

__device__ __forceinline__ void cf_body(
    int sp, int par, const short8 bfr[4], int nsp, short8 bfrN[4],
    const float* __restrict__ f_ij, const float* __restrict__ r_ij,
    const float* __restrict__ mask, const int* __restrict__ nbr,
    const unsigned short* __restrict__ fw1t,
    const unsigned short* __restrict__ ybf, float* __restrict__ out,
    float4 fb2v, short* sW1w, const short* sFw2, float (*sRed)[2][128],
    int wv, int lm, int lh, int row)
{
    // acc2 initialized with fb2 (f = jt*32+lm -> fb2v[jt]); MFMA adds on top
    floatx16 acc2[4];
#pragma unroll
    for (int jt = 0; jt < 4; ++jt) {
        float fb2j = (jt == 0) ? fb2v.x : (jt == 1) ? fb2v.y
                   : (jt == 2) ? fb2v.z : fb2v.w;
#pragma unroll
        for (int e = 0; e < 16; ++e) acc2[jt][e] = fb2j;
    }

    FijRegs Fl;
#pragma unroll
    for (int half = 0; half < 2; ++half) {
        // ---- dense1 half: ft = half*2 + {0,1}; A = fw1T (global b128,
        // L1-hot, 4 indep loads per ft), B = f_ij (regs). Results packed
        // into wave-private handoff chunk (h-local 0..63). ----
#pragma unroll
        for (int ftl = 0; ftl < 2; ++ftl) {
            const int ft = half * 2 + ftl;
            floatx16 a1;
#pragma unroll
            for (int e = 0; e < 16; ++e) a1[e] = 0.0f;
            const unsigned short* fwp = fw1t + ((ft * 32 + lm) * 64 + lh * 8);
#pragma unroll
            for (int ks = 0; ks < 4; ++ks) {
                short8 a = *(const short8*)(fwp + ks * 16);
                a1 = __builtin_amdgcn_mfma_f32_32x32x16_bf16(a, bfr[ks], a1, 0, 0, 0);
            }
            // D1 layout: col=lane&31=n; h = (reg&3)+8*(reg>>2)+4*lh (+32*ft)
#pragma unroll
            for (int q = 0; q < 8; ++q) {
                unsigned P = pk2bf(sspf(a1[2 * q]), sspf(a1[2 * q + 1]));
                int hl = ftl * 32 + 4 * lh + 8 * (q >> 1) + 2 * (q & 1);
                *(unsigned*)&sW1w[lm * SW1 + hl] = P;
            }
        }
        // ---- prefetch next body's f_ij once per body (covered by
        // dense2B + epilogue) ----
        if (half == 1 && nsp >= 0) Fl = load_fij(f_ij, nsp, row, lh);

        // ---- dense2 half: A = W1 chunk (LDS b64 pairs), B = fw2T (LDS) ----
#pragma unroll
        for (int ksl = 0; ksl < 4; ++ksl) {
            const short* ap = &sW1w[lm * SW1 + ksl * 16 + lh * 8];
            uint2 a0 = *(const uint2*)ap;
            uint2 a1v = *(const uint2*)(ap + 4);
            short8 a = mk8(a0.x, a0.y, a1v.x, a1v.y);
            const int ks = half * 4 + ksl;
#pragma unroll
            for (int jt = 0; jt < 4; ++jt) {
                const short* bp = &sFw2[(jt * 32 + lm) * SF2 + ks * 16 + lh * 8];
                uint2 b0 = *(const uint2*)bp;
                uint2 b1 = *(const uint2*)(bp + 4);
                acc2[jt] = __builtin_amdgcn_mfma_f32_32x32x16_bf16(
                    a, mk8(b0.x, b0.y, b1.x, b1.y), acc2[jt], 0, 0, 0);
            }
        }
    }

    // ---- convert prefetched f_ij now (loads long landed) ----
    if (nsp >= 0) cvt_fij(Fl, lh, bfrN);

    // ---- cutoff*mask + neighbor indices: broadcast loads, in-reg cos ----
    const int site = sp * 2 + (wv >> 1);
    float cmv[16]; int nbv[16];
#pragma unroll
    for (int rq = 0; rq < 4; ++rq) {
        int off = site * Ndim + (wv & 1) * 32 + rq * 8 + lh * 4;
        float4 r4 = *(const float4*)(r_ij + off);
        float4 m4 = *(const float4*)(mask + off);
        int4   n4 = *(const int4*)(nbr + off);
        float rr[4] = { r4.x, r4.y, r4.z, r4.w };
        float mm[4] = { m4.x, m4.y, m4.z, m4.w };
        int   nn[4] = { n4.x, n4.y, n4.z, n4.w };
#pragma unroll
        for (int j = 0; j < 4; ++j) {
            float c = 0.5f * (__cosf(rr[j] * 0.62831853071796f) + 1.0f);
            c = (rr[j] < 5.0f) ? c : 0.0f;
            cmv[rq * 4 + j] = c * mm[j];
            nbv[rq * 4 + j] = nn[j];
        }
    }

    // ---- fold cm (fb2 already inside acc2); pure mul ----
#pragma unroll
    for (int jt = 0; jt < 4; ++jt)
#pragma unroll
        for (int r = 0; r < 16; ++r)
            acc2[jt][r] *= cmv[r];

    // ---- epilogue: out[f] += acc2'[jt][r] * y2[nbr[r]][lm][jt] ----
    const int bofs = (site >> 8) * Adim;
    float part[4] = {0.f, 0.f, 0.f, 0.f};
#pragma unroll
    for (int r = 0; r < 16; ++r) {
        uint2 u = *(const uint2*)(ybf + (((size_t)(bofs + nbv[r])) << 7) + lm * 4);
        part[0] = fmaf(acc2[0][r], bf2f_lo(u.x), part[0]);
        part[1] = fmaf(acc2[1][r], bf2f_hi(u.x), part[1]);
        part[2] = fmaf(acc2[2][r], bf2f_lo(u.y), part[2]);
        part[3] = fmaf(acc2[3][r], bf2f_hi(u.y), part[3]);
    }
#pragma unroll
    for (int jt = 0; jt < 4; ++jt) part[jt] += __shfl_xor(part[jt], 32);

    const int s = wv >> 1;
    if (wv & 1) {
#pragma unroll
        for (int k = 0; k < 2; ++k)
            sRed[par][s][(2 * lh + k) * 32 + lm] = part[2 * lh + k];
    }
    __syncthreads();   // only barrier per body (sRed parity-dbuf'd)
    if (!(wv & 1)) {
#pragma unroll
        for (int k = 0; k < 2; ++k) {
            int jt = 2 * lh + k;
            int f = jt * 32 + lm;
            out[(size_t)site * Fdim + f] = part[jt] + sRed[par][s][f];
        }
    }
}

__global__ __launch_bounds__(256, 3) void cfconv_mfma11(
    const float* __restrict__ r_ij, const float* __restrict__ f_ij,
    const float* __restrict__ mask, const int* __restrict__ nbr,
    const unsigned short* __restrict__ fw1t,
    const unsigned short* __restrict__ fw2t,
    const float* __restrict__ fb2,
    const unsigned short* __restrict__ ybf, float* __restrict__ out)
{
    __shared__ short sW1[4][32][SW1];       // 17408 B: per-wave W1 handoff (half)
    __shared__ short sFw2[128 * SF2];       // 33792 B: fw2T[f][h], padded
    __shared__ float sRed[2][2][128];       //  2048 B: parity x site x f
    // total 53248 B -> 3 blocks/CU

    const int tid = threadIdx.x, wv = tid >> 6, lane = tid & 63;
    const int lm = lane & 31, lh = lane >> 5;
    const int bid = blockIdx.x;
    const int row = wv * 32 + lm;
    short* sW1w = &sW1[wv][0][0];

    // body-1 f_ij loads issued first; land while sFw2 stages
    FijRegs F0 = load_fij(f_ij, bid, row, lh);

    // stage sFw2 as raw bf16 copy from fw2t table.
    // 4096 uint2; 128-short row = 32 uint2 -> f = idx>>5, hq = idx&31.
#pragma unroll
    for (int k = 0; k < 16; ++k) {
        int idx = tid + k * 256;              // uint2 index over 4096
        int f = idx >> 5, hq = idx & 31;      // h = hq*4
        *(uint2*)&sFw2[f * SF2 + hq * 4] = *(const uint2*)(fw2t + f * 128 + hq * 4);
    }
    float4 fb2v;
    fb2v.x = fb2[lm]; fb2v.y = fb2[32 + lm]; fb2v.z = fb2[64 + lm]; fb2v.w = fb2[96 + lm];

    short8 bA[4], bB[4];
    cvt_fij(F0, lh, bA);
    __syncthreads();

    cf_body(bid, 0, bA, bid + GRID2, bB, f_ij, r_ij, mask, nbr,
            fw1t, ybf, out, fb2v, sW1w, sFw2, sRed, wv, lm, lh, row);
    cf_body(bid + GRID2, 1, bB, -1, bA, f_ij, r_ij, mask, nbr,
            fw1t, ybf, out, fb2v, sW1w, sFw2, sRed, wv, lm, lh, row);
}

// ---------------------------------------------------------------------------
extern "C" void kernel_launch(void* const* d_in, const int* in_sizes, int n_in,
                              void* d_out, int out_size, void* d_ws, size_t ws_size,
                              hipStream_t stream) {
    const float* x      = (const float*)d_in[0];
    const float* r_ij   = (const float*)d_in[1];
    const float* f_ij   = (const float*)d_in[2];
    const float* mask   = (const float*)d_in[3];
    const int*   nbr    = (const int*)d_in[4];
    const float* in2f_w = (const float*)d_in[5];
    const float* fw1    = (const float*)d_in[6];
    const float* fb1    = (const float*)d_in[7];
    const float* fw2    = (const float*)d_in[8];
    const float* fb2    = (const float*)d_in[9];
    float* out = (float*)d_out;
    unsigned short* y    = (unsigned short*)d_ws;                       // 2 MB bf16 y2
    unsigned short* fw1t = (unsigned short*)((char*)d_ws + (size_t)(Bdim*Adim*Fdim)*2);
    unsigned short* fw2t = fw1t + 128 * 64;                             // +16 KB -> 32 KB

    in2f_mfma3<<<258, 256, 0, stream>>>(x, in2f_w, y, fw1, fb1, fw2, fw1t, fw2t);
    cfconv_mfma11<<<GRID2, 256, 0, stream>>>(r_ij, f_ij, mask, nbr,
                                             fw1t, fw2t, fb2, y, out);
}

// Round 10
// 224.094 us; speedup vs baseline: 1.3892x; 1.3114x over previous
//
#include <hip/hip_runtime.h>
#include <hip/hip_bf16.h>
#include <math.h>

#define Bdim 32
#define Adim 256
#define Ndim 64
#define Gdim 50
#define Fdim 128

typedef __attribute__((ext_vector_type(8)))  short short8;
typedef __attribute__((ext_vector_type(16))) float floatx16;

__device__ __forceinline__ unsigned short f2bf_u(float x) {
    __hip_bfloat16 h = __float2bfloat16(x);
    return __builtin_bit_cast(unsigned short, h);
}
__device__ __forceinline__ unsigned pk2bf(float a, float b) {
    return (unsigned)f2bf_u(a) | ((unsigned)f2bf_u(b) << 16);
}
__device__ __forceinline__ float bf2f_lo(unsigned u) {   // low bf16 of packed u32
    return __builtin_bit_cast(float, u << 16);
}
__device__ __forceinline__ float bf2f_hi(unsigned u) {   // high bf16 of packed u32
    return __builtin_bit_cast(float, u & 0xFFFF0000u);
}
// shifted softplus = ln2*log2(1+e^v) - ln2.  5 ops / 2 trans. (verified)
__device__ __forceinline__ float sspf(float v) {
    float t = __expf(v);
    return fmaf(__log2f(1.0f + t), 0.69314718056f, -0.69314718056f);
}
__device__ __forceinline__ short8 mk8(unsigned a, unsigned b, unsigned c, unsigned d) {
    union { unsigned u[4]; short8 s; } t;
    t.u[0] = a; t.u[1] = b; t.u[2] = c; t.u[3] = d;
    return t.s;
}

// ---------------------------------------------------------------------------
// Kernel 1 v3 (verified R7+R9): y = x @ in2f_w over 256 blocks (4x CUs).
//   Block b (<256): rows b*32..b*32+31; wave wv computes jt = wv.
//   y stored INTERLEAVED: y2[row*128 + lm*4 + jt] holds f = jt*32+lm.
// Block 256: fw1T bf16 table [f][g0..63] (bias col g=50, zeros after).
// Block 257: fw2T bf16 table [f][h0..127].
// ---------------------------------------------------------------------------
__global__ __launch_bounds__(256) void in2f_mfma3(const float* __restrict__ x,
                                                  const float* __restrict__ w,
                                                  unsigned short* __restrict__ y,
                                                  const float* __restrict__ fw1,
                                                  const float* __restrict__ fb1,
                                                  const float* __restrict__ fw2,
                                                  unsigned short* __restrict__ fw1t,
                                                  unsigned short* __restrict__ fw2t) {
    const int tid = threadIdx.x;
    if (blockIdx.x == 256) {
        for (int idx = tid; idx < 128 * 64; idx += 256) {
            int f = idx >> 6, g = idx & 63;
            float v = (g < Gdim) ? fw1[g * 128 + f] : ((g == Gdim) ? fb1[f] : 0.0f);
            fw1t[idx] = f2bf_u(v);
        }
        return;
    }
    if (blockIdx.x == 257) {
        for (int idx = tid; idx < 128 * 128; idx += 256) {
            int f = idx >> 7, h = idx & 127;
            fw2t[idx] = f2bf_u(fw2[h * 128 + f]);
        }
        return;
    }
    __shared__ short sWT[128 * 132];   // w^T[f][i]  33792 B
    __shared__ short sX [32 * 132];    // x[row][i]   8448 B

#pragma unroll 4
    for (int k = 0; k < 32; ++k) {
        int idx = tid + k * 256;             // float2 index, 8192 total
        float2 v = *(const float2*)(w + 2 * idx);
        int i = idx >> 6;
        int f = (2 * idx) & 127;
        sWT[f * 132 + i]       = (short)f2bf_u(v.x);
        sWT[(f + 1) * 132 + i] = (short)f2bf_u(v.y);
    }
    const float* xb = x + (size_t)blockIdx.x * (32 * 128);
#pragma unroll
    for (int k = 0; k < 8; ++k) {
        int idx = tid + k * 256;
        float2 v = *(const float2*)(xb + 2 * idx);
        int row = idx >> 6;                  // 0..31
        int i = (2 * idx) & 127;
        *(unsigned*)&sX[row * 132 + i] = pk2bf(v.x, v.y);
    }
    __syncthreads();

    const int wv = tid >> 6, lane = tid & 63, lm = lane & 31, lh = lane >> 5;
    floatx16 acc;
#pragma unroll
    for (int e = 0; e < 16; ++e) acc[e] = 0.0f;

#pragma unroll
    for (int ks = 0; ks < 8; ++ks) {
        int g0 = ks * 16 + lh * 8;
        const short* ap = &sX[lm * 132 + g0];            // A rows = x rows = lm
        uint2 a0 = *(const uint2*)ap;
        uint2 a1 = *(const uint2*)(ap + 4);
        const short* bp = &sWT[(wv * 32 + lm) * 132 + g0];  // B rows = f
        uint2 b0 = *(const uint2*)bp;
        uint2 b1 = *(const uint2*)(bp + 4);
        acc = __builtin_amdgcn_mfma_f32_32x32x16_bf16(
            mk8(a0.x, a0.y, a1.x, a1.y), mk8(b0.x, b0.y, b1.x, b1.y), acc, 0, 0, 0);
    }
    const int rbase = blockIdx.x * 32;
#pragma unroll
    for (int r = 0; r < 16; ++r) {
        int row = rbase + (r & 3) + 8 * (r >> 2) + 4 * lh;
        y[(size_t)row * 128 + lm * 4 + wv] = f2bf_u(acc[r]);
    }
}

// ---------------------------------------------------------------------------
// Kernel 2 v12 = byte-identical restore of R6's cfconv_mfma9 (85.7 us,
// 12 MB writes, no spill).
//  R9 lesson (4th spill): even changing acc2's init from the inline
//  constant 0 to a runtime value (fb2j) perturbs allocation past the
//  (256,3) cap — zero-init lets the allocator materialize accumulators
//  with inline-constant v_accvgpr_write and remat/sink them freely.
//  ONLY provably-register-free edits are allowed in this body.
// ---------------------------------------------------------------------------
#define SF2 132     // sFw2 stride (shorts): 66 dw -> 2-way free
#define SW1 68      // handoff stride (shorts): 34 dw -> 2-way free, 8B-align
#define NSP 4096    // total super-pairs (B*A/2)
#define GRID2 2048

struct FijRegs { float2 p[13]; };

__device__ __forceinline__ FijRegs load_fij(const float* __restrict__ f_ij,
                                            int sp, int row, int lh) {
    FijRegs F;
    const float* base = f_ij + (size_t)sp * (2 * Ndim * Gdim) + row * Gdim;
#pragma unroll
    for (int ks = 0; ks < 3; ++ks) {
        int g0 = 16 * ks + 8 * lh;
#pragma unroll
        for (int j = 0; j < 4; ++j)
            F.p[ks * 4 + j] = *(const float2*)(base + g0 + 2 * j);
    }
    F.p[12] = *(const float2*)(base + 48);   // both lh halves: g=48,49
    return F;
}

// convert raw f_ij regs -> 4 packed bf16 MFMA B-frags
__device__ __forceinline__ void cvt_fij(const FijRegs& F, int lh, short8 bfr[4]) {
#pragma unroll
    for (int ks = 0; ks < 3; ++ks)
        bfr[ks] = mk8(pk2bf(F.p[ks*4+0].x, F.p[ks*4+0].y),
                      pk2bf(F.p[ks*4+1].x, F.p[ks*4+1].y),
                      pk2bf(F.p[ks*4+2].x, F.p[ks*4+2].y),
                      pk2bf(F.p[ks*4+3].x, F.p[ks*4+3].y));
    // ks=3: lh=0 holds g=48,49, bias 1.0 at g=50, zeros; lh=1 all zero
    unsigned u0 = lh ? 0u : pk2bf(F.p[12].x, F.p[12].y);
    unsigned u1 = lh ? 0u : 0x00003F80u;
    bfr[3] = mk8(u0, u1, 0u, 0u);
}

__device__ __forceinline__ void cf_body(
    int sp, int par, const short8 bfr[4], int nsp, short8 bfrN[4],
    const float* __restrict__ f_ij, const float* __restrict__ r_ij,
    const float* __restrict__ mask, const int* __restrict__ nbr,
    const unsigned short* __restrict__ fw1t,
    const unsigned short* __restrict__ ybf, float* __restrict__ out,
    float4 fb2v, short* sW1w, const short* sFw2, float (*sRed)[2][128],
    int wv, int lm, int lh, int row)
{
    // acc2 zero-init (inline-constant accvgpr writes — do NOT change)
    floatx16 acc2[4];
#pragma unroll
    for (int jt = 0; jt < 4; ++jt)
#pragma unroll
        for (int e = 0; e < 16; ++e) acc2[jt][e] = 0.0f;

    FijRegs Fl;
#pragma unroll
    for (int half = 0; half < 2; ++half) {
        // ---- dense1 half: ft = half*2 + {0,1}; A = fw1T (global b128,
        // L1-hot, 4 indep loads per ft), B = f_ij (regs). Results packed
        // into wave-private handoff chunk (h-local 0..63). ----
#pragma unroll
        for (int ftl = 0; ftl < 2; ++ftl) {
            const int ft = half * 2 + ftl;
            floatx16 a1;
#pragma unroll
            for (int e = 0; e < 16; ++e) a1[e] = 0.0f;
            const unsigned short* fwp = fw1t + ((ft * 32 + lm) * 64 + lh * 8);
#pragma unroll
            for (int ks = 0; ks < 4; ++ks) {
                short8 a = *(const short8*)(fwp + ks * 16);
                a1 = __builtin_amdgcn_mfma_f32_32x32x16_bf16(a, bfr[ks], a1, 0, 0, 0);
            }
            // D1 layout: col=lane&31=n; h = (reg&3)+8*(reg>>2)+4*lh (+32*ft)
#pragma unroll
            for (int q = 0; q < 8; ++q) {
                unsigned P = pk2bf(sspf(a1[2 * q]), sspf(a1[2 * q + 1]));
                int hl = ftl * 32 + 4 * lh + 8 * (q >> 1) + 2 * (q & 1);
                *(unsigned*)&sW1w[lm * SW1 + hl] = P;
            }
        }
        // ---- prefetch next body's f_ij once per body (covered by
        // dense2B + epilogue) ----
        if (half == 1 && nsp >= 0) Fl = load_fij(f_ij, nsp, row, lh);

        // ---- dense2 half: A = W1 chunk (LDS b64 pairs), B = fw2T (LDS) ----
#pragma unroll
        for (int ksl = 0; ksl < 4; ++ksl) {
            const short* ap = &sW1w[lm * SW1 + ksl * 16 + lh * 8];
            uint2 a0 = *(const uint2*)ap;
            uint2 a1v = *(const uint2*)(ap + 4);
            short8 a = mk8(a0.x, a0.y, a1v.x, a1v.y);
            const int ks = half * 4 + ksl;
#pragma unroll
            for (int jt = 0; jt < 4; ++jt) {
                const short* bp = &sFw2[(jt * 32 + lm) * SF2 + ks * 16 + lh * 8];
                uint2 b0 = *(const uint2*)bp;
                uint2 b1 = *(const uint2*)(bp + 4);
                acc2[jt] = __builtin_amdgcn_mfma_f32_32x32x16_bf16(
                    a, mk8(b0.x, b0.y, b1.x, b1.y), acc2[jt], 0, 0, 0);
            }
        }
    }

    // ---- convert prefetched f_ij now (loads long landed) ----
    if (nsp >= 0) cvt_fij(Fl, lh, bfrN);

    // ---- cutoff*mask + neighbor indices: broadcast loads, in-reg cos ----
    const int site = sp * 2 + (wv >> 1);
    float cmv[16]; int nbv[16];
#pragma unroll
    for (int rq = 0; rq < 4; ++rq) {
        int off = site * Ndim + (wv & 1) * 32 + rq * 8 + lh * 4;
        float4 r4 = *(const float4*)(r_ij + off);
        float4 m4 = *(const float4*)(mask + off);
        int4   n4 = *(const int4*)(nbr + off);
        float rr[4] = { r4.x, r4.y, r4.z, r4.w };
        float mm[4] = { m4.x, m4.y, m4.z, m4.w };
        int   nn[4] = { n4.x, n4.y, n4.z, n4.w };
#pragma unroll
        for (int j = 0; j < 4; ++j) {
            float c = 0.5f * (__cosf(rr[j] * 0.62831853071796f) + 1.0f);
            c = (rr[j] < 5.0f) ? c : 0.0f;
            cmv[rq * 4 + j] = c * mm[j];
            nbv[rq * 4 + j] = nn[j];
        }
    }

    // ---- fold (acc2+fb2)*cm once; epilogue loop is pure fma ----
#pragma unroll
    for (int jt = 0; jt < 4; ++jt) {
        float fb2j = (jt == 0) ? fb2v.x : (jt == 1) ? fb2v.y
                   : (jt == 2) ? fb2v.z : fb2v.w;
#pragma unroll
        for (int r = 0; r < 16; ++r)
            acc2[jt][r] = (acc2[jt][r] + fb2j) * cmv[r];
    }

    // ---- epilogue: out[f] += acc2'[jt][r] * y2[nbr[r]][lm][jt] ----
    const int bofs = (site >> 8) * Adim;
    float part[4] = {0.f, 0.f, 0.f, 0.f};
#pragma unroll
    for (int r = 0; r < 16; ++r) {
        uint2 u = *(const uint2*)(ybf + (((size_t)(bofs + nbv[r])) << 7) + lm * 4);
        part[0] = fmaf(acc2[0][r], bf2f_lo(u.x), part[0]);
        part[1] = fmaf(acc2[1][r], bf2f_hi(u.x), part[1]);
        part[2] = fmaf(acc2[2][r], bf2f_lo(u.y), part[2]);
        part[3] = fmaf(acc2[3][r], bf2f_hi(u.y), part[3]);
    }
#pragma unroll
    for (int jt = 0; jt < 4; ++jt) part[jt] += __shfl_xor(part[jt], 32);

    const int s = wv >> 1;
    if (wv & 1) {
#pragma unroll
        for (int k = 0; k < 2; ++k)
            sRed[par][s][(2 * lh + k) * 32 + lm] = part[2 * lh + k];
    }
    __syncthreads();   // only barrier per body (sRed parity-dbuf'd)
    if (!(wv & 1)) {
#pragma unroll
        for (int k = 0; k < 2; ++k) {
            int jt = 2 * lh + k;
            int f = jt * 32 + lm;
            out[(size_t)site * Fdim + f] = part[jt] + sRed[par][s][f];
        }
    }
}

__global__ __launch_bounds__(256, 3) void cfconv_mfma12(
    const float* __restrict__ r_ij, const float* __restrict__ f_ij,
    const float* __restrict__ mask, const int* __restrict__ nbr,
    const unsigned short* __restrict__ fw1t,
    const unsigned short* __restrict__ fw2t,
    const float* __restrict__ fb2,
    const unsigned short* __restrict__ ybf, float* __restrict__ out)
{
    __shared__ short sW1[4][32][SW1];       // 17408 B: per-wave W1 handoff (half)
    __shared__ short sFw2[128 * SF2];       // 33792 B: fw2T[f][h], padded
    __shared__ float sRed[2][2][128];       //  2048 B: parity x site x f
    // total 53248 B -> 3 blocks/CU

    const int tid = threadIdx.x, wv = tid >> 6, lane = tid & 63;
    const int lm = lane & 31, lh = lane >> 5;
    const int bid = blockIdx.x;
    const int row = wv * 32 + lm;
    short* sW1w = &sW1[wv][0][0];

    // body-1 f_ij loads issued first; land while sFw2 stages
    FijRegs F0 = load_fij(f_ij, bid, row, lh);

    // stage sFw2 as raw bf16 copy from fw2t table.
    // 4096 uint2; 128-short row = 32 uint2 -> f = idx>>5, hq = idx&31.
#pragma unroll
    for (int k = 0; k < 16; ++k) {
        int idx = tid + k * 256;              // uint2 index over 4096
        int f = idx >> 5, hq = idx & 31;      // h = hq*4
        *(uint2*)&sFw2[f * SF2 + hq * 4] = *(const uint2*)(fw2t + f * 128 + hq * 4);
    }
    float4 fb2v;
    fb2v.x = fb2[lm]; fb2v.y = fb2[32 + lm]; fb2v.z = fb2[64 + lm]; fb2v.w = fb2[96 + lm];

    short8 bA[4], bB[4];
    cvt_fij(F0, lh, bA);
    __syncthreads();

    cf_body(bid, 0, bA, bid + GRID2, bB, f_ij, r_ij, mask, nbr,
            fw1t, ybf, out, fb2v, sW1w, sFw2, sRed, wv, lm, lh, row);
    cf_body(bid + GRID2, 1, bB, -1, bA, f_ij, r_ij, mask, nbr,
            fw1t, ybf, out, fb2v, sW1w, sFw2, sRed, wv, lm, lh, row);
}

// ---------------------------------------------------------------------------
extern "C" void kernel_launch(void* const* d_in, const int* in_sizes, int n_in,
                              void* d_out, int out_size, void* d_ws, size_t ws_size,
                              hipStream_t stream) {
    const float* x      = (const float*)d_in[0];
    const float* r_ij   = (const float*)d_in[1];
    const float* f_ij   = (const float*)d_in[2];
    const float* mask   = (const float*)d_in[3];
    const int*   nbr    = (const int*)d_in[4];
    const float* in2f_w = (const float*)d_in[5];
    const float* fw1    = (const float*)d_in[6];
    const float* fb1    = (const float*)d_in[7];
    const float* fw2    = (const float*)d_in[8];
    const float* fb2    = (const float*)d_in[9];
    float* out = (float*)d_out;
    unsigned short* y    = (unsigned short*)d_ws;                       // 2 MB bf16 y2
    unsigned short* fw1t = (unsigned short*)((char*)d_ws + (size_t)(Bdim*Adim*Fdim)*2);
    unsigned short* fw2t = fw1t + 128 * 64;                             // +16 KB -> 32 KB

    in2f_mfma3<<<258, 256, 0, stream>>>(x, in2f_w, y, fw1, fb1, fw2, fw1t, fw2t);
    cfconv_mfma12<<<GRID2, 256, 0, stream>>>(r_ij, f_ij, mask, nbr,
                                             fw1t, fw2t, fb2, y, out);
}

// Round 11
// 220.852 us; speedup vs baseline: 1.4096x; 1.0147x over previous
//
#include <hip/hip_runtime.h>
#include <hip/hip_bf16.h>
#include <math.h>

#define Bdim 32
#define Adim 256
#define Ndim 64
#define Gdim 50
#define Fdim 128

typedef __attribute__((ext_vector_type(8)))  short short8;
typedef __attribute__((ext_vector_type(16))) float floatx16;

__device__ __forceinline__ unsigned short f2bf_u(float x) {
    __hip_bfloat16 h = __float2bfloat16(x);
    return __builtin_bit_cast(unsigned short, h);
}
__device__ __forceinline__ unsigned pk2bf(float a, float b) {
    return (unsigned)f2bf_u(a) | ((unsigned)f2bf_u(b) << 16);
}
__device__ __forceinline__ float bf2f_lo(unsigned u) {   // low bf16 of packed u32
    return __builtin_bit_cast(float, u << 16);
}
__device__ __forceinline__ float bf2f_hi(unsigned u) {   // high bf16 of packed u32
    return __builtin_bit_cast(float, u & 0xFFFF0000u);
}
// shifted softplus = ln2*log2(1+e^v) - ln2.  5 ops / 2 trans. (verified)
__device__ __forceinline__ float sspf(float v) {
    float t = __expf(v);
    return fmaf(__log2f(1.0f + t), 0.69314718056f, -0.69314718056f);
}
__device__ __forceinline__ short8 mk8(unsigned a, unsigned b, unsigned c, unsigned d) {
    union { unsigned u[4]; short8 s; } t;
    t.u[0] = a; t.u[1] = b; t.u[2] = c; t.u[3] = d;
    return t.s;
}

// ---------------------------------------------------------------------------
// Kernel 0: prep all bf16 weight tables (one gather+cvt+store per element).
//   wt  [f][i]  (16384): w^T for in2f          (w   layout: [i][f])
//   fw2t[f][h]  (16384): fw2^T for cfconv      (fw2 layout: [h][f])
//   fw1t[f][g64] (8192): fw1^T+bias for cfconv (fw1 layout: [g][f])
// grid 64 x 256 = 16384 threads; each: 1 wt + 1 fw2t + (gid<8192: 1 fw1t).
// ---------------------------------------------------------------------------
__global__ __launch_bounds__(256) void prep_tables(const float* __restrict__ w,
                                                   const float* __restrict__ fw1,
                                                   const float* __restrict__ fb1,
                                                   const float* __restrict__ fw2,
                                                   unsigned short* __restrict__ wt,
                                                   unsigned short* __restrict__ fw1t,
                                                   unsigned short* __restrict__ fw2t) {
    const int gid = blockIdx.x * 256 + threadIdx.x;   // 0..16383
    {
        int f = gid >> 7, i = gid & 127;
        wt[gid] = f2bf_u(w[i * 128 + f]);
        fw2t[gid] = f2bf_u(fw2[i * 128 + f]);         // i plays h here
    }
    if (gid < 128 * 64) {
        int f = gid >> 6, g = gid & 63;
        float v = (g < Gdim) ? fw1[g * 128 + f] : ((g == Gdim) ? fb1[f] : 0.0f);
        fw1t[gid] = f2bf_u(v);
    }
}

// ---------------------------------------------------------------------------
// Kernel 1 v4: y = x @ in2f_w with ZERO LDS / ZERO barriers.
//   R10 null result: 256-block split didn't help because every block still
//   staged the full w^T through LDS (serial prologue, 1 wave/SIMD = no TLP).
//   v4: B-frags = 8 aligned b128 loads from L2-hot wt table; A-frags = 2
//   float4 x-loads per ks direct from global (x tile L1-resident) + pk2bf.
//   All loads independent -> full memory-level parallelism.
//   y stored INTERLEAVED (unchanged): y2[row*128 + lm*4 + jt], jt = wv.
// ---------------------------------------------------------------------------
__global__ __launch_bounds__(256) void in2f_mfma4(const float* __restrict__ x,
                                                  const unsigned short* __restrict__ wt,
                                                  unsigned short* __restrict__ y) {
    const int tid = threadIdx.x, wv = tid >> 6, lane = tid & 63;
    const int lm = lane & 31, lh = lane >> 5;
    const float* xb = x + (size_t)blockIdx.x * (32 * 128);

    // 8 B-frags from wt (row f = wv*32+lm), issued upfront (32 VGPR)
    short8 bw[8];
#pragma unroll
    for (int ks = 0; ks < 8; ++ks)
        bw[ks] = *(const short8*)(wt + (wv * 32 + lm) * 128 + ks * 16 + lh * 8);

    floatx16 acc;
#pragma unroll
    for (int e = 0; e < 16; ++e) acc[e] = 0.0f;

#pragma unroll
    for (int ks = 0; ks < 8; ++ks) {
        const float* ap = xb + lm * 128 + ks * 16 + lh * 8;   // x row = lm
        float4 a0 = *(const float4*)ap;
        float4 a1 = *(const float4*)(ap + 4);
        short8 a = mk8(pk2bf(a0.x, a0.y), pk2bf(a0.z, a0.w),
                       pk2bf(a1.x, a1.y), pk2bf(a1.z, a1.w));
        acc = __builtin_amdgcn_mfma_f32_32x32x16_bf16(a, bw[ks], acc, 0, 0, 0);
    }
    const int rbase = blockIdx.x * 32;
#pragma unroll
    for (int r = 0; r < 16; ++r) {
        int row = rbase + (r & 3) + 8 * (r >> 2) + 4 * lh;
        y[(size_t)row * 128 + lm * 4 + wv] = f2bf_u(acc[r]);
    }
}

// ---------------------------------------------------------------------------
// Kernel 2 v12 (byte-identical to R6/R10 verified 85.7 us — DO NOT TOUCH).
//  Four spills (R2/R3/R7/R9) prove this body is at the (256,3) register
//  cliff; even constant->runtime accumulator-init changes spill it.
// ---------------------------------------------------------------------------
#define SF2 132     // sFw2 stride (shorts): 66 dw -> 2-way free
#define SW1 68      // handoff stride (shorts): 34 dw -> 2-way free, 8B-align
#define NSP 4096    // total super-pairs (B*A/2)
#define GRID2 2048

struct FijRegs { float2 p[13]; };

__device__ __forceinline__ FijRegs load_fij(const float* __restrict__ f_ij,
                                            int sp, int row, int lh) {
    FijRegs F;
    const float* base = f_ij + (size_t)sp * (2 * Ndim * Gdim) + row * Gdim;
#pragma unroll
    for (int ks = 0; ks < 3; ++ks) {
        int g0 = 16 * ks + 8 * lh;
#pragma unroll
        for (int j = 0; j < 4; ++j)
            F.p[ks * 4 + j] = *(const float2*)(base + g0 + 2 * j);
    }
    F.p[12] = *(const float2*)(base + 48);   // both lh halves: g=48,49
    return F;
}

// convert raw f_ij regs -> 4 packed bf16 MFMA B-frags
__device__ __forceinline__ void cvt_fij(const FijRegs& F, int lh, short8 bfr[4]) {
#pragma unroll
    for (int ks = 0; ks < 3; ++ks)
        bfr[ks] = mk8(pk2bf(F.p[ks*4+0].x, F.p[ks*4+0].y),
                      pk2bf(F.p[ks*4+1].x, F.p[ks*4+1].y),
                      pk2bf(F.p[ks*4+2].x, F.p[ks*4+2].y),
                      pk2bf(F.p[ks*4+3].x, F.p[ks*4+3].y));
    // ks=3: lh=0 holds g=48,49, bias 1.0 at g=50, zeros; lh=1 all zero
    unsigned u0 = lh ? 0u : pk2bf(F.p[12].x, F.p[12].y);
    unsigned u1 = lh ? 0u : 0x00003F80u;
    bfr[3] = mk8(u0, u1, 0u, 0u);
}

__device__ __forceinline__ void cf_body(
    int sp, int par, const short8 bfr[4], int nsp, short8 bfrN[4],
    const float* __restrict__ f_ij, const float* __restrict__ r_ij,
    const float* __restrict__ mask, const int* __restrict__ nbr,
    const unsigned short* __restrict__ fw1t,
    const unsigned short* __restrict__ ybf, float* __restrict__ out,
    float4 fb2v, short* sW1w, const short* sFw2, float (*sRed)[2][128],
    int wv, int lm, int lh, int row)
{
    // acc2 zero-init (inline-constant accvgpr writes — do NOT change)
    floatx16 acc2[4];
#pragma unroll
    for (int jt = 0; jt < 4; ++jt)
#pragma unroll
        for (int e = 0; e < 16; ++e) acc2[jt][e] = 0.0f;

    FijRegs Fl;
#pragma unroll
    for (int half = 0; half < 2; ++half) {
        // ---- dense1 half: ft = half*2 + {0,1}; A = fw1T (global b128,
        // L1-hot, 4 indep loads per ft), B = f_ij (regs). Results packed
        // into wave-private handoff chunk (h-local 0..63). ----
#pragma unroll
        for (int ftl = 0; ftl < 2; ++ftl) {
            const int ft = half * 2 + ftl;
            floatx16 a1;
#pragma unroll
            for (int e = 0; e < 16; ++e) a1[e] = 0.0f;
            const unsigned short* fwp = fw1t + ((ft * 32 + lm) * 64 + lh * 8);
#pragma unroll
            for (int ks = 0; ks < 4; ++ks) {
                short8 a = *(const short8*)(fwp + ks * 16);
                a1 = __builtin_amdgcn_mfma_f32_32x32x16_bf16(a, bfr[ks], a1, 0, 0, 0);
            }
            // D1 layout: col=lane&31=n; h = (reg&3)+8*(reg>>2)+4*lh (+32*ft)
#pragma unroll
            for (int q = 0; q < 8; ++q) {
                unsigned P = pk2bf(sspf(a1[2 * q]), sspf(a1[2 * q + 1]));
                int hl = ftl * 32 + 4 * lh + 8 * (q >> 1) + 2 * (q & 1);
                *(unsigned*)&sW1w[lm * SW1 + hl] = P;
            }
        }
        // ---- prefetch next body's f_ij once per body (covered by
        // dense2B + epilogue) ----
        if (half == 1 && nsp >= 0) Fl = load_fij(f_ij, nsp, row, lh);

        // ---- dense2 half: A = W1 chunk (LDS b64 pairs), B = fw2T (LDS) ----
#pragma unroll
        for (int ksl = 0; ksl < 4; ++ksl) {
            const short* ap = &sW1w[lm * SW1 + ksl * 16 + lh * 8];
            uint2 a0 = *(const uint2*)ap;
            uint2 a1v = *(const uint2*)(ap + 4);
            short8 a = mk8(a0.x, a0.y, a1v.x, a1v.y);
            const int ks = half * 4 + ksl;
#pragma unroll
            for (int jt = 0; jt < 4; ++jt) {
                const short* bp = &sFw2[(jt * 32 + lm) * SF2 + ks * 16 + lh * 8];
                uint2 b0 = *(const uint2*)bp;
                uint2 b1 = *(const uint2*)(bp + 4);
                acc2[jt] = __builtin_amdgcn_mfma_f32_32x32x16_bf16(
                    a, mk8(b0.x, b0.y, b1.x, b1.y), acc2[jt], 0, 0, 0);
            }
        }
    }

    // ---- convert prefetched f_ij now (loads long landed) ----
    if (nsp >= 0) cvt_fij(Fl, lh, bfrN);

    // ---- cutoff*mask + neighbor indices: broadcast loads, in-reg cos ----
    const int site = sp * 2 + (wv >> 1);
    float cmv[16]; int nbv[16];
#pragma unroll
    for (int rq = 0; rq < 4; ++rq) {
        int off = site * Ndim + (wv & 1) * 32 + rq * 8 + lh * 4;
        float4 r4 = *(const float4*)(r_ij + off);
        float4 m4 = *(const float4*)(mask + off);
        int4   n4 = *(const int4*)(nbr + off);
        float rr[4] = { r4.x, r4.y, r4.z, r4.w };
        float mm[4] = { m4.x, m4.y, m4.z, m4.w };
        int   nn[4] = { n4.x, n4.y, n4.z, n4.w };
#pragma unroll
        for (int j = 0; j < 4; ++j) {
            float c = 0.5f * (__cosf(rr[j] * 0.62831853071796f) + 1.0f);
            c = (rr[j] < 5.0f) ? c : 0.0f;
            cmv[rq * 4 + j] = c * mm[j];
            nbv[rq * 4 + j] = nn[j];
        }
    }

    // ---- fold (acc2+fb2)*cm once; epilogue loop is pure fma ----
#pragma unroll
    for (int jt = 0; jt < 4; ++jt) {
        float fb2j = (jt == 0) ? fb2v.x : (jt == 1) ? fb2v.y
                   : (jt == 2) ? fb2v.z : fb2v.w;
#pragma unroll
        for (int r = 0; r < 16; ++r)
            acc2[jt][r] = (acc2[jt][r] + fb2j) * cmv[r];
    }

    // ---- epilogue: out[f] += acc2'[jt][r] * y2[nbr[r]][lm][jt] ----
    const int bofs = (site >> 8) * Adim;
    float part[4] = {0.f, 0.f, 0.f, 0.f};
#pragma unroll
    for (int r = 0; r < 16; ++r) {
        uint2 u = *(const uint2*)(ybf + (((size_t)(bofs + nbv[r])) << 7) + lm * 4);
        part[0] = fmaf(acc2[0][r], bf2f_lo(u.x), part[0]);
        part[1] = fmaf(acc2[1][r], bf2f_hi(u.x), part[1]);
        part[2] = fmaf(acc2[2][r], bf2f_lo(u.y), part[2]);
        part[3] = fmaf(acc2[3][r], bf2f_hi(u.y), part[3]);
    }
#pragma unroll
    for (int jt = 0; jt < 4; ++jt) part[jt] += __shfl_xor(part[jt], 32);

    const int s = wv >> 1;
    if (wv & 1) {
#pragma unroll
        for (int k = 0; k < 2; ++k)
            sRed[par][s][(2 * lh + k) * 32 + lm] = part[2 * lh + k];
    }
    __syncthreads();   // only barrier per body (sRed parity-dbuf'd)
    if (!(wv & 1)) {
#pragma unroll
        for (int k = 0; k < 2; ++k) {
            int jt = 2 * lh + k;
            int f = jt * 32 + lm;
            out[(size_t)site * Fdim + f] = part[jt] + sRed[par][s][f];
        }
    }
}

__global__ __launch_bounds__(256, 3) void cfconv_mfma12(
    const float* __restrict__ r_ij, const float* __restrict__ f_ij,
    const float* __restrict__ mask, const int* __restrict__ nbr,
    const unsigned short* __restrict__ fw1t,
    const unsigned short* __restrict__ fw2t,
    const float* __restrict__ fb2,
    const unsigned short* __restrict__ ybf, float* __restrict__ out)
{
    __shared__ short sW1[4][32][SW1];       // 17408 B: per-wave W1 handoff (half)
    __shared__ short sFw2[128 * SF2];       // 33792 B: fw2T[f][h], padded
    __shared__ float sRed[2][2][128];       //  2048 B: parity x site x f
    // total 53248 B -> 3 blocks/CU

    const int tid = threadIdx.x, wv = tid >> 6, lane = tid & 63;
    const int lm = lane & 31, lh = lane >> 5;
    const int bid = blockIdx.x;
    const int row = wv * 32 + lm;
    short* sW1w = &sW1[wv][0][0];

    // body-1 f_ij loads issued first; land while sFw2 stages
    FijRegs F0 = load_fij(f_ij, bid, row, lh);

    // stage sFw2 as raw bf16 copy from fw2t table.
    // 4096 uint2; 128-short row = 32 uint2 -> f = idx>>5, hq = idx&31.
#pragma unroll
    for (int k = 0; k < 16; ++k) {
        int idx = tid + k * 256;              // uint2 index over 4096
        int f = idx >> 5, hq = idx & 31;      // h = hq*4
        *(uint2*)&sFw2[f * SF2 + hq * 4] = *(const uint2*)(fw2t + f * 128 + hq * 4);
    }
    float4 fb2v;
    fb2v.x = fb2[lm]; fb2v.y = fb2[32 + lm]; fb2v.z = fb2[64 + lm]; fb2v.w = fb2[96 + lm];

    short8 bA[4], bB[4];
    cvt_fij(F0, lh, bA);
    __syncthreads();

    cf_body(bid, 0, bA, bid + GRID2, bB, f_ij, r_ij, mask, nbr,
            fw1t, ybf, out, fb2v, sW1w, sFw2, sRed, wv, lm, lh, row);
    cf_body(bid + GRID2, 1, bB, -1, bA, f_ij, r_ij, mask, nbr,
            fw1t, ybf, out, fb2v, sW1w, sFw2, sRed, wv, lm, lh, row);
}

// ---------------------------------------------------------------------------
extern "C" void kernel_launch(void* const* d_in, const int* in_sizes, int n_in,
                              void* d_out, int out_size, void* d_ws, size_t ws_size,
                              hipStream_t stream) {
    const float* x      = (const float*)d_in[0];
    const float* r_ij   = (const float*)d_in[1];
    const float* f_ij   = (const float*)d_in[2];
    const float* mask   = (const float*)d_in[3];
    const int*   nbr    = (const int*)d_in[4];
    const float* in2f_w = (const float*)d_in[5];
    const float* fw1    = (const float*)d_in[6];
    const float* fb1    = (const float*)d_in[7];
    const float* fw2    = (const float*)d_in[8];
    const float* fb2    = (const float*)d_in[9];
    float* out = (float*)d_out;
    unsigned short* y    = (unsigned short*)d_ws;                       // 2 MB bf16 y2
    unsigned short* fw1t = (unsigned short*)((char*)d_ws + (size_t)(Bdim*Adim*Fdim)*2);
    unsigned short* fw2t = fw1t + 128 * 64;                             // +16 KB
    unsigned short* wt   = fw2t + 128 * 128;                            // +32 KB

    prep_tables<<<64, 256, 0, stream>>>(in2f_w, fw1, fb1, fw2, wt, fw1t, fw2t);
    in2f_mfma4<<<256, 256, 0, stream>>>(x, wt, y);
    cfconv_mfma12<<<GRID2, 256, 0, stream>>>(r_ij, f_ij, mask, nbr,
                                             fw1t, fw2t, fb2, y, out);
}